// Round 15
// baseline (71.214 us; speedup 1.0000x reference)
//
#include <hip/hip_runtime.h>
#include <hip/hip_bf16.h>
#include <hip/hip_fp16.h>
#include <cstddef>

#define BN 4096
#define DD 128
#define NSTEPS 100
#define PTILE 128
#define PLSTR 136   // bf16 elems per LDS row: 128 + 8 pad -> 272 B stride
#define GRID_T (BN / PTILE)   // 32
#define NOFF 496    // strictly-upper tile pairs (ti<tj)
#define NBLK 528    // + 32 diagonal tiles
#define HSLOT 101   // floats per POS-histogram slot
#define NREP 16     // POS histogram replicas (keyed by lane&15)
#define HROWS 101   // 100 bins + 1 dump row for merged duplicates

typedef __attribute__((ext_vector_type(8))) short bf16x8;
typedef __attribute__((ext_vector_type(4))) float f32x4;

// HW fp atomic. Measured (r2-r9): LDS fp-atomic lane-ops ~6.3 cyc CU-serialized
// regardless of address pattern -> atomics ONLY on the rare (~1%) POS path.
__device__ __forceinline__ void faddf(float* p, float v) {
    unsafeAtomicAdd(p, v);
}

// ---------------- normalize + convert to bf16: one wave per row ----------------
__global__ __launch_bounds__(256) void hl_normalize(const float* __restrict__ emb,
                                                    ushort* __restrict__ out) {
    int w = threadIdx.x >> 6;
    int lane = threadIdx.x & 63;
    int row = (blockIdx.x << 2) + w;
    const float2 v = *(const float2*)(emb + (size_t)row * DD + 2 * lane);
    float ss = v.x * v.x + v.y * v.y;
    #pragma unroll
    for (int off = 32; off > 0; off >>= 1) ss += __shfl_xor(ss, off);
    float inv = 1.0f / sqrtf(ss);
    __hip_bfloat16 b0 = __float2bfloat16(v.x * inv);
    __hip_bfloat16 b1 = __float2bfloat16(v.y * inv);
    ushort2 pk;
    pk.x = *(ushort*)&b0;
    pk.y = *(ushort*)&b1;
    *(ushort2*)(out + (size_t)row * DD + 2 * lane) = pk;
}

// ---------------- pair kernel: 128x128 tile pairs via bf16 MFMA ----------------
// gHist layout: [0..99] = ALL bins, [100..199] = POS bins  (neg = all - pos)
__global__ __launch_bounds__(256, 2) void hl_pair(const ushort* __restrict__ nemb,
                                                  const int* __restrict__ cls,
                                                  float* __restrict__ gHist) {
    // flat grid: blocks 0..495 = strictly-upper tile pairs, 496..527 = diagonal
    int ti, tj;
    {
        int t = blockIdx.x;
        if (t < NOFF) {
            ti = 0;
            int rem = t;
            while (rem >= GRID_T - 1 - ti) { rem -= GRID_T - 1 - ti; ++ti; }
            tj = ti + 1 + rem;
        } else {
            ti = tj = t - NOFF;
        }
    }

    // arena: tiles (69632 B) during MFMA; per-thread fp16 ALL-hist (51712 B) after
    __shared__ __align__(16) char arena[2 * PTILE * PLSTR * sizeof(ushort)];
    ushort* As = (ushort*)arena;
    ushort* Bs = As + PTILE * PLSTR;
    _Float16* hallh = (_Float16*)arena;           // [HROWS][256] per-thread columns
    uint* hall32 = (uint*)arena;                  // same, as uint pairs
    __shared__ float hpos[NREP * HSLOT];          // 6464 B, fp32 atomic POS path
    __shared__ int clsA[PTILE], clsB[PTILE];

    const int tid = threadIdx.x;
    if (tid < PTILE) clsA[tid] = cls[ti * PTILE + tid];
    else             clsB[tid - PTILE] = cls[tj * PTILE + (tid - PTILE)];

    // stage A and B tiles
    #pragma unroll
    for (int it = 0; it < 8; ++it) {
        int idx = it * 256 + tid;
        int row = idx >> 4;
        int c = idx & 15;
        const float4 va = *(const float4*)(nemb + (size_t)(ti * PTILE + row) * DD + c * 8);
        const float4 vb = *(const float4*)(nemb + (size_t)(tj * PTILE + row) * DD + c * 8);
        *(float4*)(&As[row * PLSTR + c * 8]) = va;
        *(float4*)(&Bs[row * PLSTR + c * 8]) = vb;
    }
    __syncthreads();

    const int lane = tid & 63;
    const int wid = tid >> 6;
    const int wr = wid >> 1, wc = wid & 1;
    const int lr = lane & 15;
    const int kg = lane >> 4;

    f32x4 zero4 = {0.f, 0.f, 0.f, 0.f};
    f32x4 acc[4][4];
    #pragma unroll
    for (int a = 0; a < 4; ++a)
        #pragma unroll
        for (int b = 0; b < 4; ++b) acc[a][b] = zero4;

    #pragma unroll
    for (int ks = 0; ks < 4; ++ks) {
        bf16x8 af[4], bfr[4];
        #pragma unroll
        for (int f = 0; f < 4; ++f) {
            int arow = wr * 64 + f * 16 + lr;
            af[f] = *(const bf16x8*)(&As[arow * PLSTR + ks * 32 + kg * 8]);
            int brow = wc * 64 + f * 16 + lr;
            bfr[f] = *(const bf16x8*)(&Bs[brow * PLSTR + ks * 32 + kg * 8]);
        }
        #pragma unroll
        for (int fa = 0; fa < 4; ++fa)
            #pragma unroll
            for (int fb = 0; fb < 4; ++fb)
                acc[fa][fb] = __builtin_amdgcn_mfma_f32_16x16x32_bf16(af[fa], bfr[fb], acc[fa][fb], 0, 0, 0);
    }

    // tiles dead; zero fp16 ALL-hist (overlay, incl. dump row) and POS-hist
    __syncthreads();
    #pragma unroll 8
    for (int i = tid; i < HROWS * 128; i += 256) hall32[i] = 0u;   // 51712 B as uints
    for (int i = tid; i < NREP * HSLOT; i += 256) hpos[i] = 0.f;
    __syncthreads();

    // ---- histogram epilogue: 4-pair batches, register collision-merge, ----
    // ---- 8 parallel fp16 RMWs per batch; atomic rare POS path           ----
    constexpr float STEPF = 2.0f / 99.0f;
    constexpr float INVSTEP = 49.5f;
    constexpr float CLIPV = 1.0f - 1e-6f;

    const int li_base = wr * 64 + (kg << 2);
    const int lj_base = wc * 64 + lr;
    const int posrep = (lane & 15) * HSLOT;

    int ca[16];
    #pragma unroll
    for (int fa = 0; fa < 4; ++fa)
        #pragma unroll
        for (int j = 0; j < 4; ++j) ca[fa * 4 + j] = clsA[li_base + fa * 16 + j];

    const bool offdiag = (ti != tj);

    #pragma unroll
    for (int fb = 0; fb < 4; ++fb) {
        const int lj = lj_base + fb * 16;
        const int cb = clsB[lj];
        #pragma unroll
        for (int fa = 0; fa < 4; ++fa) {
            const int li0 = li_base + fa * 16;
            f32x4 v = acc[fa][fb];

            int addr8[8];
            float w8[8];
            #pragma unroll
            for (int j = 0; j < 4; ++j) {
                const int li = li0 + j;
                const bool valid = offdiag || (li < lj);
                float s = v[j];
                s = fminf(fmaxf(s, -CLIPV), CLIPV);
                float u = (s + CLIPV) * INVSTEP;
                int jb = (int)u;
                if (jb > 98) jb = 98;
                float t_j = (float)jb * STEPF - 1.0f;
                float vm = valid ? 1.0f : 0.0f;          // mask into weights
                float w_hi = (s - t_j) * INVSTEP * vm;
                float w_lo = vm - w_hi;
                addr8[2 * j] = jb;       w8[2 * j] = w_lo;
                addr8[2 * j + 1] = jb + 1; w8[2 * j + 1] = w_hi;
                if (valid && ca[fa * 4 + j] == cb) {     // ~1% of pairs
                    faddf(&hpos[posrep + jb], w_lo);
                    faddf(&hpos[posrep + jb + 1], w_hi);
                }
            }

            // merge duplicate targets (exact): later slot folds into earlier,
            // then redirects to dump row 100 -> 8 independent RMW addresses
            #pragma unroll
            for (int k = 1; k < 8; ++k)
                #pragma unroll
                for (int m = 0; m < k; ++m) {
                    bool e = (addr8[k] == addr8[m]);
                    w8[m] += e ? w8[k] : 0.f;
                    w8[k] = e ? 0.f : w8[k];
                    addr8[k] = e ? 100 : addr8[k];
                }

            // 8 reads in flight -> one wait -> 8 adds -> 8 writes
            _Float16 old8[8];
            #pragma unroll
            for (int k = 0; k < 8; ++k) old8[k] = hallh[addr8[k] * 256 + tid];
            #pragma unroll
            for (int k = 0; k < 8; ++k)
                hallh[addr8[k] * 256 + tid] = old8[k] + (_Float16)w8[k];
        }
    }
    __syncthreads();

    // reduce: bin b summed by threads b (cols 0..127) and b+128 (cols 128..255),
    // staggered (r+b)&127 uint indexing -> conflict-free
    if (tid < NSTEPS) {
        const int b = tid;
        float ssum = 0.f;
        #pragma unroll 8
        for (int r = 0; r < 64; ++r) {
            uint u2 = hall32[b * 128 + ((r + b) & 127)];
            __half2 h2 = *(__half2*)&u2;
            ssum += __low2float(h2) + __high2float(h2);
        }
        faddf(&gHist[b], ssum);
        float psum = 0.f;
        #pragma unroll
        for (int rp = 0; rp < NREP; ++rp) psum += hpos[rp * HSLOT + b];
        faddf(&gHist[NSTEPS + b], psum);
    } else if (tid >= 128 && tid < 128 + NSTEPS) {
        const int b = tid - 128;
        float ssum = 0.f;
        #pragma unroll 8
        for (int r = 64; r < 128; ++r) {
            uint u2 = hall32[b * 128 + ((r + b) & 127)];
            __half2 h2 = *(__half2*)&u2;
            ssum += __low2float(h2) + __high2float(h2);
        }
        faddf(&gHist[b], ssum);
    }
}

// ---------------- finalize: cumsum + dot, 128-thread scan ----------------
__global__ __launch_bounds__(128) void hl_final(const float* __restrict__ gHist,
                                                float* __restrict__ out) {
    __shared__ float spA[128], snA[128], sc[128], red[128];
    const int t = threadIdx.x;
    float p = (t < NSTEPS) ? gHist[NSTEPS + t] : 0.f;               // POS
    float n = (t < NSTEPS) ? (gHist[t] - gHist[NSTEPS + t]) : 0.f;  // NEG = ALL - POS
    spA[t] = p; snA[t] = n;
    __syncthreads();
    #pragma unroll
    for (int off = 64; off > 0; off >>= 1) {
        if (t < off) { spA[t] += spA[t + off]; snA[t] += snA[t + off]; }
        __syncthreads();
    }
    const float sp = spA[0], sn = snA[0];
    sc[t] = p;
    __syncthreads();
    #pragma unroll
    for (int off = 1; off < 128; off <<= 1) {
        float v = (t >= off) ? sc[t - off] : 0.f;
        __syncthreads();
        sc[t] += v;
        __syncthreads();
    }
    red[t] = n * sc[t];
    __syncthreads();
    #pragma unroll
    for (int off = 64; off > 0; off >>= 1) {
        if (t < off) red[t] += red[t + off];
        __syncthreads();
    }
    if (t == 0) out[0] = red[0] / (sp * sn);
}

extern "C" void kernel_launch(void* const* d_in, const int* in_sizes, int n_in,
                              void* d_out, int out_size, void* d_ws, size_t ws_size,
                              hipStream_t stream) {
    const float* emb = (const float*)d_in[0];
    const int* classes = (const int*)d_in[1];
    float* out = (float*)d_out;

    ushort* nemb = (ushort*)d_ws;                                 // 4096*128 bf16 = 1 MB
    float* gHist = (float*)((char*)d_ws + (size_t)BN * DD * sizeof(ushort));  // 200 floats

    hipMemsetAsync(gHist, 0, 2 * NSTEPS * sizeof(float), stream);

    hl_normalize<<<BN / 4, 256, 0, stream>>>(emb, nemb);

    hl_pair<<<NBLK, 256, 0, stream>>>(nemb, classes, gHist);

    hl_final<<<1, 128, 0, stream>>>(gHist, out);
}

// Round 16
// 68.222 us; speedup vs baseline: 1.0438x; 1.0438x over previous
//
#include <hip/hip_runtime.h>
#include <hip/hip_bf16.h>
#include <hip/hip_fp16.h>
#include <cstddef>

#define BN 4096
#define DD 128
#define NSTEPS 100
#define PTILE 128
#define GRID_T (BN / PTILE)   // 32
#define NOFF 496    // strictly-upper tile pairs (ti<tj)
#define NBLK 528    // + 32 diagonal tiles
#define HSLOT 101   // floats per POS-histogram slot
#define NREP 4      // POS histogram replicas (keyed by lane&3)
#define HROWS 100

typedef __attribute__((ext_vector_type(8))) short bf16x8;
typedef __attribute__((ext_vector_type(4))) float f32x4;

// HW fp atomic. Measured (r2-r9): LDS fp-atomic lane-ops ~6.3 cyc CU-serialized
// regardless of address pattern -> atomics ONLY on the rare (~1%) POS path.
__device__ __forceinline__ void faddf(float* p, float v) {
    unsafeAtomicAdd(p, v);
}

// ---------------- normalize + convert to bf16: one wave per row ----------------
__global__ __launch_bounds__(256) void hl_normalize(const float* __restrict__ emb,
                                                    ushort* __restrict__ out) {
    int w = threadIdx.x >> 6;
    int lane = threadIdx.x & 63;
    int row = (blockIdx.x << 2) + w;
    const float2 v = *(const float2*)(emb + (size_t)row * DD + 2 * lane);
    float ss = v.x * v.x + v.y * v.y;
    #pragma unroll
    for (int off = 32; off > 0; off >>= 1) ss += __shfl_xor(ss, off);
    float inv = 1.0f / sqrtf(ss);
    __hip_bfloat16 b0 = __float2bfloat16(v.x * inv);
    __hip_bfloat16 b1 = __float2bfloat16(v.y * inv);
    ushort2 pk;
    pk.x = *(ushort*)&b0;
    pk.y = *(ushort*)&b1;
    *(ushort2*)(out + (size_t)row * DD + 2 * lane) = pk;
}

// ---------------- pair kernel: 128x128 tile pairs via bf16 MFMA ----------------
// No LDS tile staging: MFMA fragments stream from global (L2-resident, ~34MB
// total). LDS = histograms only (53.8KB) -> 3 blocks/CU -> 528 blocks in ONE
// round with 24 resident waves/CU.
// gHist layout: [0..99] = ALL bins, [100..199] = POS bins  (neg = all - pos)
__global__ __launch_bounds__(256, 3) void hl_pair(const ushort* __restrict__ nemb,
                                                  const int* __restrict__ cls,
                                                  float* __restrict__ gHist) {
    // flat grid: blocks 0..495 = strictly-upper tile pairs, 496..527 = diagonal
    int ti, tj;
    {
        int t = blockIdx.x;
        if (t < NOFF) {
            ti = 0;
            int rem = t;
            while (rem >= GRID_T - 1 - ti) { rem -= GRID_T - 1 - ti; ++ti; }
            tj = ti + 1 + rem;
        } else {
            ti = tj = t - NOFF;
        }
    }

    __shared__ _Float16 hallh[HROWS * 256];       // 51200 B per-thread columns
    uint* hall32 = (uint*)hallh;
    __shared__ float hpos[NREP * HSLOT];          // 1616 B, fp32 atomic POS path
    __shared__ int clsA[PTILE], clsB[PTILE];

    const int tid = threadIdx.x;
    if (tid < PTILE) clsA[tid] = cls[ti * PTILE + tid];
    else             clsB[tid - PTILE] = cls[tj * PTILE + (tid - PTILE)];

    // zero hists up front (overlaps with MFMA-phase global loads)
    #pragma unroll 8
    for (int i = tid; i < HROWS * 128; i += 256) hall32[i] = 0u;
    for (int i = tid; i < NREP * HSLOT; i += 256) hpos[i] = 0.f;

    const int lane = tid & 63;
    const int wid = tid >> 6;
    const int wr = wid >> 1, wc = wid & 1;
    const int lr = lane & 15;
    const int kg = lane >> 4;

    f32x4 zero4 = {0.f, 0.f, 0.f, 0.f};
    f32x4 acc[4][4];
    #pragma unroll
    for (int a = 0; a < 4; ++a)
        #pragma unroll
        for (int b = 0; b < 4; ++b) acc[a][b] = zero4;

    const ushort* Abase = nemb + (size_t)(ti * PTILE) * DD;
    const ushort* Bbase = nemb + (size_t)(tj * PTILE) * DD;

    #pragma unroll
    for (int ks = 0; ks < 4; ++ks) {
        bf16x8 af[4], bfr[4];
        #pragma unroll
        for (int f = 0; f < 4; ++f) {
            int arow = wr * 64 + f * 16 + lr;
            af[f] = *(const bf16x8*)(Abase + (size_t)arow * DD + ks * 32 + kg * 8);
            int brow = wc * 64 + f * 16 + lr;
            bfr[f] = *(const bf16x8*)(Bbase + (size_t)brow * DD + ks * 32 + kg * 8);
        }
        #pragma unroll
        for (int fa = 0; fa < 4; ++fa)
            #pragma unroll
            for (int fb = 0; fb < 4; ++fb)
                acc[fa][fb] = __builtin_amdgcn_mfma_f32_16x16x32_bf16(af[fa], bfr[fb], acc[fa][fb], 0, 0, 0);
    }

    __syncthreads();   // hist zero + cls visible; acc complete

    // ---- histogram epilogue: branch-free fp16 per-thread ALL, atomic rare POS ----
    constexpr float STEPF = 2.0f / 99.0f;
    constexpr float INVSTEP = 49.5f;
    constexpr float CLIPV = 1.0f - 1e-6f;

    const int li_base = wr * 64 + (kg << 2);
    const int lj_base = wc * 64 + lr;
    const int posrep = (lane & 3) * HSLOT;

    int ca[16];
    #pragma unroll
    for (int fa = 0; fa < 4; ++fa)
        #pragma unroll
        for (int j = 0; j < 4; ++j) ca[fa * 4 + j] = clsA[li_base + fa * 16 + j];

    const bool offdiag = (ti != tj);

    #pragma unroll
    for (int fb = 0; fb < 4; ++fb) {
        const int lj = lj_base + fb * 16;
        const int cb = clsB[lj];
        #pragma unroll
        for (int fa = 0; fa < 4; ++fa) {
            const int li0 = li_base + fa * 16;
            f32x4 v = acc[fa][fb];
            #pragma unroll
            for (int j = 0; j < 4; ++j) {
                const int li = li0 + j;
                const bool valid = offdiag || (li < lj);
                float s = v[j];
                s = fminf(fmaxf(s, -CLIPV), CLIPV);
                float u = (s + CLIPV) * INVSTEP;
                int jb = (int)u;
                if (jb > 98) jb = 98;
                float t_j = (float)jb * STEPF - 1.0f;
                float vm = valid ? 1.0f : 0.0f;          // mask into weights: no branch
                float w_hi = (s - t_j) * INVSTEP * vm;
                float w_lo = vm - w_hi;
                int base = jb * 256 + tid;               // own column: no race
                _Float16 lo = hallh[base];
                _Float16 hi = hallh[base + 256];
                hallh[base] = lo + (_Float16)w_lo;       // plain ds_read/ds_write
                hallh[base + 256] = hi + (_Float16)w_hi;
                if (valid && ca[fa * 4 + j] == cb) {     // ~1% of pairs
                    faddf(&hpos[posrep + jb], w_lo);
                    faddf(&hpos[posrep + jb + 1], w_hi);
                }
            }
        }
    }
    __syncthreads();

    // reduce: bin b summed by threads b (cols 0..127) and b+128 (cols 128..255),
    // staggered (r+b)&127 uint indexing -> conflict-free
    if (tid < NSTEPS) {
        const int b = tid;
        float ssum = 0.f;
        #pragma unroll 8
        for (int r = 0; r < 64; ++r) {
            uint u2 = hall32[b * 128 + ((r + b) & 127)];
            __half2 h2 = *(__half2*)&u2;
            ssum += __low2float(h2) + __high2float(h2);
        }
        faddf(&gHist[b], ssum);
        float psum = 0.f;
        #pragma unroll
        for (int rp = 0; rp < NREP; ++rp) psum += hpos[rp * HSLOT + b];
        faddf(&gHist[NSTEPS + b], psum);
    } else if (tid >= 128 && tid < 128 + NSTEPS) {
        const int b = tid - 128;
        float ssum = 0.f;
        #pragma unroll 8
        for (int r = 64; r < 128; ++r) {
            uint u2 = hall32[b * 128 + ((r + b) & 127)];
            __half2 h2 = *(__half2*)&u2;
            ssum += __low2float(h2) + __high2float(h2);
        }
        faddf(&gHist[b], ssum);
    }
}

// ---------------- finalize: cumsum + dot, 128-thread scan ----------------
__global__ __launch_bounds__(128) void hl_final(const float* __restrict__ gHist,
                                                float* __restrict__ out) {
    __shared__ float spA[128], snA[128], sc[128], red[128];
    const int t = threadIdx.x;
    float p = (t < NSTEPS) ? gHist[NSTEPS + t] : 0.f;               // POS
    float n = (t < NSTEPS) ? (gHist[t] - gHist[NSTEPS + t]) : 0.f;  // NEG = ALL - POS
    spA[t] = p; snA[t] = n;
    __syncthreads();
    #pragma unroll
    for (int off = 64; off > 0; off >>= 1) {
        if (t < off) { spA[t] += spA[t + off]; snA[t] += snA[t + off]; }
        __syncthreads();
    }
    const float sp = spA[0], sn = snA[0];
    sc[t] = p;
    __syncthreads();
    #pragma unroll
    for (int off = 1; off < 128; off <<= 1) {
        float v = (t >= off) ? sc[t - off] : 0.f;
        __syncthreads();
        sc[t] += v;
        __syncthreads();
    }
    red[t] = n * sc[t];
    __syncthreads();
    #pragma unroll
    for (int off = 64; off > 0; off >>= 1) {
        if (t < off) red[t] += red[t + off];
        __syncthreads();
    }
    if (t == 0) out[0] = red[0] / (sp * sn);
}

extern "C" void kernel_launch(void* const* d_in, const int* in_sizes, int n_in,
                              void* d_out, int out_size, void* d_ws, size_t ws_size,
                              hipStream_t stream) {
    const float* emb = (const float*)d_in[0];
    const int* classes = (const int*)d_in[1];
    float* out = (float*)d_out;

    ushort* nemb = (ushort*)d_ws;                                 // 4096*128 bf16 = 1 MB
    float* gHist = (float*)((char*)d_ws + (size_t)BN * DD * sizeof(ushort));  // 200 floats

    hipMemsetAsync(gHist, 0, 2 * NSTEPS * sizeof(float), stream);

    hl_normalize<<<BN / 4, 256, 0, stream>>>(emb, nemb);

    hl_pair<<<NBLK, 256, 0, stream>>>(nemb, classes, gHist);

    hl_final<<<1, 128, 0, stream>>>(gHist, out);
}